// Round 3
// baseline (94.347 us; speedup 1.0000x reference)
//
#include <hip/hip_runtime.h>

#define D_CLAMP 10.0f
#define EPS_F   1e-4f
#define Z_F     10.0f
#define I_TILE  4

// Each block owns I_TILE consecutive frames (i) of one batch b; frame constants
// (Rp, -Rt, -c : 21 floats/frame) live in registers. 256 threads stride over j.
// Per 6 loads we issue I_TILE*24 = 96 pure-FMA-dominated VALU instrs (16:1),
// so L2-hit load latency is hidden at 4 waves/SIMD.
__global__ __launch_bounds__(256) void fape_kernel(
    const float* __restrict__ pred_rot,   // [B,N,3,3]
    const float* __restrict__ pred_trans, // [B,N,3]
    const float* __restrict__ pred_pos,   // [B,N,3]
    const float* __restrict__ true_rot,   // [B,N,3,3]
    const float* __restrict__ true_trans, // [B,N,3]
    const float* __restrict__ true_pos,   // [B,N,3]
    float* __restrict__ out,              // [B]
    int N)
{
    const int tilesPerB = (N + I_TILE - 1) / I_TILE;
    const int b  = blockIdx.x / tilesPerB;
    const int i0 = (blockIdx.x % tilesPerB) * I_TILE;

    // (R^T v)[o] = R[p*3+o] * v[p] summed over p.
    float rp[I_TILE][9], rtn[I_TILE][9], ccn[I_TILE][3], w[I_TILE];
#pragma unroll
    for (int k = 0; k < I_TILE; ++k) {
        const int ii = i0 + k;
        const int iv = ii < N ? ii : N - 1;
        w[k] = ii < N ? 1.0f : 0.0f;
        const size_t fi = (size_t)b * N + iv;
        const float* Rp = pred_rot + fi * 9;
        const float* Rt = true_rot + fi * 9;
        float rt[9];
#pragma unroll
        for (int q = 0; q < 9; ++q) { rp[k][q] = Rp[q]; rt[q] = Rt[q]; rtn[k][q] = -Rt[q]; }
        const float* tpv = pred_trans + fi * 3;
        const float* ttv = true_trans + fi * 3;
        const float tp0 = tpv[0], tp1 = tpv[1], tp2 = tpv[2];
        const float tt0 = ttv[0], tt1 = ttv[1], tt2 = ttv[2];
        // ccn = -( Rp^T tp - Rt^T tt )
#pragma unroll
        for (int o = 0; o < 3; ++o) {
            ccn[k][o] = (rt[0+o]*tt0 + rt[3+o]*tt1 + rt[6+o]*tt2)
                      - (rp[k][0+o]*tp0 + rp[k][3+o]*tp1 + rp[k][6+o]*tp2);
        }
    }

    const float* xp = pred_pos + (size_t)b * N * 3;
    const float* xt = true_pos + (size_t)b * N * 3;

    float sum = 0.0f;
#pragma unroll 2
    for (int j = threadIdx.x; j < N; j += 256) {
        const float a0 = xp[3*j+0], a1 = xp[3*j+1], a2 = xp[3*j+2];
        const float b0 = xt[3*j+0], b1 = xt[3*j+1], b2 = xt[3*j+2];
#pragma unroll
        for (int k = 0; k < I_TILE; ++k) {
            // d_o = rp·a + rtn·b + ccn  -> 6 FMAs per component, zero subtracts
            const float d0 = fmaf(rp[k][0], a0, fmaf(rp[k][3], a1, fmaf(rp[k][6], a2,
                             fmaf(rtn[k][0], b0, fmaf(rtn[k][3], b1, fmaf(rtn[k][6], b2, ccn[k][0]))))));
            const float d1 = fmaf(rp[k][1], a0, fmaf(rp[k][4], a1, fmaf(rp[k][7], a2,
                             fmaf(rtn[k][1], b0, fmaf(rtn[k][4], b1, fmaf(rtn[k][7], b2, ccn[k][1]))))));
            const float d2 = fmaf(rp[k][2], a0, fmaf(rp[k][5], a1, fmaf(rp[k][8], a2,
                             fmaf(rtn[k][2], b0, fmaf(rtn[k][5], b1, fmaf(rtn[k][8], b2, ccn[k][2]))))));
            const float d2sum = fmaf(d0, d0, fmaf(d1, d1, fmaf(d2, d2, EPS_F)));
            const float dist = __builtin_amdgcn_sqrtf(d2sum);
            sum = fmaf(w[k], fminf(dist, D_CLAMP), sum);
        }
    }

    // Wave (64-lane) shuffle reduction.
#pragma unroll
    for (int off = 32; off > 0; off >>= 1)
        sum += __shfl_down(sum, off, 64);

    __shared__ float smem[4];
    const int lane = threadIdx.x & 63;
    const int wave = threadIdx.x >> 6;
    if (lane == 0) smem[wave] = sum;
    __syncthreads();

    if (threadIdx.x == 0) {
        const float s = smem[0] + smem[1] + smem[2] + smem[3];
        const float scale = 1.0f / (Z_F * (float)N * (float)N);
        atomicAdd(out + b, s * scale);
    }
}

extern "C" void kernel_launch(void* const* d_in, const int* in_sizes, int n_in,
                              void* d_out, int out_size, void* d_ws, size_t ws_size,
                              hipStream_t stream) {
    const float* pred_rot   = (const float*)d_in[0];
    const float* pred_trans = (const float*)d_in[1];
    const float* pred_pos   = (const float*)d_in[2];
    const float* true_rot   = (const float*)d_in[3];
    const float* true_trans = (const float*)d_in[4];
    const float* true_pos   = (const float*)d_in[5];
    float* out = (float*)d_out;

    const int B = out_size;                  // 4
    const int BN = in_sizes[1] / 3;          // B*N
    const int N = BN / B;                    // 2048

    const int tilesPerB = (N + I_TILE - 1) / I_TILE;

    hipMemsetAsync(out, 0, (size_t)out_size * sizeof(float), stream);
    fape_kernel<<<B * tilesPerB, 256, 0, stream>>>(pred_rot, pred_trans, pred_pos,
                                                   true_rot, true_trans, true_pos,
                                                   out, N);
}

// Round 4
// 86.930 us; speedup vs baseline: 1.0853x; 1.0853x over previous
//
#include <hip/hip_runtime.h>

#define D_CLAMP 10.0f
#define EPS_F   1e-4f
#define Z_F     10.0f
#define JT 2          // atoms per thread, held in VGPRs
#define IC 32         // frames (i) per block

// ---------------------------------------------------------------------------
// Pass 1: per-frame constants -> d_ws.  For each frame f = (b,i):
//   cons[f][0..8]  = Rp (row-major, used as (R^T v)[o] = C[p*3+o]*v[p])
//   cons[f][9..17] = -Rt
//   cons[f][18..20]= -(Rp^T tp - Rt^T tt)
//   cons[f][21..23]= pad (96 B stride, s_load friendly)
// ---------------------------------------------------------------------------
__global__ __launch_bounds__(256) void fape_pre(
    const float* __restrict__ pred_rot, const float* __restrict__ pred_trans,
    const float* __restrict__ true_rot, const float* __restrict__ true_trans,
    float* __restrict__ cons, int total)
{
    const int f = blockIdx.x * 256 + threadIdx.x;
    if (f >= total) return;
    const float* Rp = pred_rot + (size_t)f * 9;
    const float* Rt = true_rot + (size_t)f * 9;
    float rp[9], rt[9];
#pragma unroll
    for (int q = 0; q < 9; ++q) { rp[q] = Rp[q]; rt[q] = Rt[q]; }
    const float* tpv = pred_trans + (size_t)f * 3;
    const float* ttv = true_trans + (size_t)f * 3;
    const float tp0 = tpv[0], tp1 = tpv[1], tp2 = tpv[2];
    const float tt0 = ttv[0], tt1 = ttv[1], tt2 = ttv[2];

    float* C = cons + (size_t)f * 24;
#pragma unroll
    for (int q = 0; q < 9; ++q) { C[q] = rp[q]; C[9 + q] = -rt[q]; }
#pragma unroll
    for (int o = 0; o < 3; ++o) {
        C[18 + o] = (rt[0+o]*tt0 + rt[3+o]*tt1 + rt[6+o]*tt2)
                  - (rp[0+o]*tp0 + rp[3+o]*tp1 + rp[6+o]*tp2);
    }
    C[21] = 0.0f; C[22] = 0.0f; C[23] = 0.0f;
}

// ---------------------------------------------------------------------------
// Pass 2: main loop. Each thread holds JT atoms (12 floats) in VGPRs, loaded
// ONCE. Loop over IC frames; per-frame constants are wave-uniform -> SGPRs via
// the scalar pipe (no vector memory in the hot loop at all).
// ---------------------------------------------------------------------------
__global__ __launch_bounds__(256) void fape_main(
    const float* __restrict__ pred_pos,  // [B,N,3]
    const float* __restrict__ true_pos,  // [B,N,3]
    const float* __restrict__ cons,      // [B*N,24]
    float* __restrict__ out,             // [B]
    int N, int iChunks, int jChunks)
{
    const int ic = blockIdx.x % iChunks;
    const int jc = (blockIdx.x / iChunks) % jChunks;
    const int b  = blockIdx.x / (iChunks * jChunks);

    const int j0 = (jc * 256 + threadIdx.x) * JT;
    const int j0c = j0 < N - JT ? j0 : (N - JT > 0 ? N - JT : 0);
    float wj0 = (j0 + 0 < N) ? 1.0f : 0.0f;
    float wj1 = (j0 + 1 < N) ? 1.0f : 0.0f;

    // Load this thread's JT=2 atoms (pred & true) once: 12 floats via float2.
    const float2* xp2 = (const float2*)(pred_pos + ((size_t)b * N + j0c) * 3);
    const float2* xt2 = (const float2*)(true_pos + ((size_t)b * N + j0c) * 3);
    const float2 p0 = xp2[0], p1 = xp2[1], p2 = xp2[2];
    const float2 q0 = xt2[0], q1 = xt2[1], q2 = xt2[2];
    const float a00 = p0.x, a01 = p0.y, a02 = p1.x;   // atom 0 pred
    const float a10 = p1.y, a11 = p2.x, a12 = p2.y;   // atom 1 pred
    const float b00 = q0.x, b01 = q0.y, b02 = q1.x;   // atom 0 true
    const float b10 = q1.y, b11 = q2.x, b12 = q2.y;   // atom 1 true

    const int i0 = ic * IC;
    const float* Cb = cons + ((size_t)b * N + i0) * 24;

    float sum = 0.0f;
#pragma unroll 2
    for (int it = 0; it < IC; ++it) {
        const int i = i0 + it;
        const float wI = (i < N) ? 1.0f : 0.0f;
        const float w0 = wI * wj0, w1 = wI * wj1;
        const float* C = Cb + it * 24;   // wave-uniform -> s_load
        float c[21];
#pragma unroll
        for (int q = 0; q < 21; ++q) c[q] = C[q];

        // atom 0
        {
            const float d0 = fmaf(c[0], a00, fmaf(c[3], a01, fmaf(c[6], a02,
                             fmaf(c[9], b00, fmaf(c[12], b01, fmaf(c[15], b02, c[18]))))));
            const float d1 = fmaf(c[1], a00, fmaf(c[4], a01, fmaf(c[7], a02,
                             fmaf(c[10], b00, fmaf(c[13], b01, fmaf(c[16], b02, c[19]))))));
            const float d2 = fmaf(c[2], a00, fmaf(c[5], a01, fmaf(c[8], a02,
                             fmaf(c[11], b00, fmaf(c[14], b01, fmaf(c[17], b02, c[20]))))));
            const float s2 = fmaf(d0, d0, fmaf(d1, d1, fmaf(d2, d2, EPS_F)));
            sum = fmaf(w0, fminf(__builtin_amdgcn_sqrtf(s2), D_CLAMP), sum);
        }
        // atom 1
        {
            const float d0 = fmaf(c[0], a10, fmaf(c[3], a11, fmaf(c[6], a12,
                             fmaf(c[9], b10, fmaf(c[12], b11, fmaf(c[15], b12, c[18]))))));
            const float d1 = fmaf(c[1], a10, fmaf(c[4], a11, fmaf(c[7], a12,
                             fmaf(c[10], b10, fmaf(c[13], b11, fmaf(c[16], b12, c[19]))))));
            const float d2 = fmaf(c[2], a10, fmaf(c[5], a11, fmaf(c[8], a12,
                             fmaf(c[11], b10, fmaf(c[14], b11, fmaf(c[17], b12, c[20]))))));
            const float s2 = fmaf(d0, d0, fmaf(d1, d1, fmaf(d2, d2, EPS_F)));
            sum = fmaf(w1, fminf(__builtin_amdgcn_sqrtf(s2), D_CLAMP), sum);
        }
    }

    // Wave (64-lane) shuffle reduction.
#pragma unroll
    for (int off = 32; off > 0; off >>= 1)
        sum += __shfl_down(sum, off, 64);

    __shared__ float smem[4];
    const int lane = threadIdx.x & 63;
    const int wave = threadIdx.x >> 6;
    if (lane == 0) smem[wave] = sum;
    __syncthreads();

    if (threadIdx.x == 0) {
        const float s = smem[0] + smem[1] + smem[2] + smem[3];
        const float scale = 1.0f / (Z_F * (float)N * (float)N);
        atomicAdd(out + b, s * scale);
    }
}

extern "C" void kernel_launch(void* const* d_in, const int* in_sizes, int n_in,
                              void* d_out, int out_size, void* d_ws, size_t ws_size,
                              hipStream_t stream) {
    const float* pred_rot   = (const float*)d_in[0];
    const float* pred_trans = (const float*)d_in[1];
    const float* pred_pos   = (const float*)d_in[2];
    const float* true_rot   = (const float*)d_in[3];
    const float* true_trans = (const float*)d_in[4];
    const float* true_pos   = (const float*)d_in[5];
    float* out = (float*)d_out;

    const int B = out_size;                  // 4
    const int BN = in_sizes[1] / 3;          // B*N
    const int N = BN / B;                    // 2048

    float* cons = (float*)d_ws;              // BN*24*4 = 786 KB, fits d_ws

    hipMemsetAsync(out, 0, (size_t)out_size * sizeof(float), stream);
    fape_pre<<<(BN + 255) / 256, 256, 0, stream>>>(pred_rot, pred_trans,
                                                   true_rot, true_trans,
                                                   cons, BN);
    const int jChunks = (N + 256 * JT - 1) / (256 * JT);   // 4
    const int iChunks = (N + IC - 1) / IC;                 // 64
    fape_main<<<B * jChunks * iChunks, 256, 0, stream>>>(pred_pos, true_pos,
                                                         cons, out,
                                                         N, iChunks, jChunks);
}